// Round 2
// baseline (408.038 us; speedup 1.0000x reference)
//
#include <hip/hip_runtime.h>
#include <hip/hip_bf16.h>

// CausalDiscoveryModule: B=256, N=512, E=32, IN=512, K=10
// out[b,i,j] = gate_b * sigmoid(logit) on per-(b,i)-row top-10 of j, else 0
// logit = sum_e (c_b^2 * emb_i)[e] * emb_j[e]
//
// R7 (base = R5 compute; R6's LDS row-compose epilogue FAILED):
//  - R6 post-mortem: LDS scatter (float*) vs vector read (nf4*) are
//    differently-typed pointers; alias analysis reordered scatter/read/rezero
//    across the unrolled row loop -> rows emitted before their values landed
//    (absmax 0.55 = full sigmoid*gate values missing). In-wave DS ordering is
//    a HW fact but NOT a compiler contract.
//  - R7 epilogue: same single-pass dense-write idea, but row compose is in
//    REGISTERS via v_readlane broadcast (owner index is wave-uniform -> SGPR
//    broadcast). Each lane owns 8 floats of the row (lo: [4*lane,4*lane+4),
//    hi: [256+4*lane,...)); 10 broadcast (j,val) pairs are merged with
//    branchless selects on uniform (half,elem) + per-lane lane==j>>2 compare.
//    Pure dataflow: nothing for the compiler to reorder. No vmcnt(0), no LDS,
//    every output cache line written exactly once (268MB total, ~43us floor;
//    R5's fill+scatter paid ~84MB L2 RMW fetch + ~84MB re-write on top).

#define NUM_VARS 512
#define EMBED_DIM 32
#define IN_DIM 512
#define BATCH 256

typedef float nf4 __attribute__((ext_vector_type(4)));
typedef float f2 __attribute__((ext_vector_type(2)));

// ---------------- K1: context MLP -> w = c^2 [256][32], gate [256] ----------
__global__ __launch_bounds__(256) void cdm_k1(
    const float* __restrict__ ctx, const float* __restrict__ W1,
    const float* __restrict__ b1, const float* __restrict__ W2,
    const float* __restrict__ b2, const float* __restrict__ Wg,
    const float* __restrict__ bg, float* __restrict__ wws,
    float* __restrict__ gws) {
  const int bb = blockIdx.x;
  const int t = threadIdx.x;
  __shared__ float xs[512];
  __shared__ float psum[32][9];   // +1 pad
  __shared__ float hs[32];
  __shared__ float cs[32];
  const float* x = ctx + (bb << 9);
  xs[t] = x[t];
  xs[t + 256] = x[t + 256];
  __syncthreads();
  {
    const int e = t >> 3, part = t & 7;
    const float* wrow = W1 + e * 512 + part * 64;
    const float* xp = xs + part * 64;
    float a = 0.f;
#pragma unroll
    for (int m = 0; m < 64; ++m) a = fmaf(wrow[m], xp[m], a);
    psum[e][part] = a;
  }
  __syncthreads();
  if (t < 32) {
    float a = 0.f;
#pragma unroll
    for (int p = 0; p < 8; ++p) a += psum[t][p];
    hs[t] = fmaxf(a + b1[t], 0.f);
  }
  __syncthreads();
  if (t < 32) {
    const float* wrow = W2 + (t << 5);
    float a = 0.f;
#pragma unroll
    for (int k = 0; k < 32; ++k) a = fmaf(wrow[k], hs[k], a);
    float c = a + b2[t];
    cs[t] = c;
    wws[(bb << 5) + t] = c * c;
  }
  __syncthreads();
  if (t == 0) {
    float a = 0.f;
#pragma unroll
    for (int k = 0; k < 32; ++k) a = fmaf(Wg[k], cs[k], a);
    float g = a + bg[0];
    gws[bb] = 1.f / (1.f + __expf(-g));
  }
}

// strict-> shift insert: equal values keep earlier-inserted (lower j) above
#define TOP10_INSERT(av, aj, v, jn)                           \
  do {                                                        \
    _Pragma("unroll") for (int k = 9; k >= 1; --k) {          \
      bool gk = (v) > av[k];                                  \
      bool gk1 = (v) > av[k - 1];                             \
      av[k] = gk ? (gk1 ? av[k - 1] : (v)) : av[k];           \
      aj[k] = gk ? (gk1 ? aj[k - 1] : (jn)) : aj[k];          \
    }                                                         \
    bool g0 = (v) > av[0];                                    \
    av[0] = g0 ? (v) : av[0];                                 \
    aj[0] = g0 ? (jn) : aj[0];                                \
  } while (0)

// ---------------- K2: 2-wave block per 64 rows; exact top-10; dense write ---
__global__ __launch_bounds__(128, 4) void cdm_k2(
    const float* __restrict__ emb, const float* __restrict__ wws,
    const float* __restrict__ gws, float* __restrict__ out) {
  const int lane = threadIdx.x & 63;
  const int w = threadIdx.x >> 6;    // half 0: j in [0,256), 1: [256,512)
  const int G = __builtin_amdgcn_readfirstlane(blockIdx.x);
  const int r0 = G << 6;             // 64 rows per block, same b
  const int b = r0 >> 9;
  const int i = (r0 + lane) & 511;
  const int jbase = __builtin_amdgcn_readfirstlane(w << 8);

  __shared__ float mvv[2][10][64];   // lane-minor: conflict-free
  __shared__ int mjj[2][10][64];

  // sv2[q] = (c^2)[b] * emb[i] as float2 pairs (per-lane)
  f2 sv2[16];
  {
    const f2* wb = reinterpret_cast<const f2*>(wws + (b << 5));
    const f2* ei = reinterpret_cast<const f2*>(emb + (i << 5));
#pragma unroll
    for (int q = 0; q < 16; ++q) sv2[q] = wb[q] * ei[q];
  }
  const float gateb = gws[b];

  float hv[10];
  int hj[10];
#pragma unroll
  for (int k = 0; k < 10; ++k) { hv[k] = -1e30f; hj[k] = 0; }

  const f2* eb = reinterpret_cast<const f2*>(emb);
  for (int t = 0; t < 64; ++t) {
    const int j0 = jbase + (t << 2);
    const f2* e0 = eb + ((j0 + 0) << 4);
    const f2* e1 = eb + ((j0 + 1) << 4);
    const f2* e2 = eb + ((j0 + 2) << 4);
    const f2* e3 = eb + ((j0 + 3) << 4);
    f2 c0 = {0.f, 0.f}, c1 = {0.f, 0.f}, c2 = {0.f, 0.f}, c3 = {0.f, 0.f};
#pragma unroll
    for (int q = 0; q < 16; ++q) {
      c0 += sv2[q] * e0[q];   // v_pk_fma_f32
      c1 += sv2[q] * e1[q];
      c2 += sv2[q] * e2[q];
      c3 += sv2[q] * e3[q];
    }
    float a0 = c0.x + c0.y, a1 = c1.x + c1.y;
    float a2 = c2.x + c2.y, a3 = c3.x + c3.y;

    const float thr = hv[9];
    int p0 = a0 > thr, p1 = a1 > thr, p2 = a2 > thr, p3 = a3 > thr;
    while (__any(p0 | p1 | p2 | p3)) {
      if (p0 | p1 | p2 | p3) {
        float v;
        int jn;
        if (p0) { v = a0; jn = j0; p0 = 0; }
        else if (p1) { v = a1; jn = j0 + 1; p1 = 0; }
        else if (p2) { v = a2; jn = j0 + 2; p2 = 0; }
        else { v = a3; jn = j0 + 3; p3 = 0; }
        TOP10_INSERT(hv, hj, v, jn);
      }
      const float nt = hv[9];
      p0 = p0 && (a0 > nt);
      p1 = p1 && (a1 > nt);
      p2 = p2 && (a2 > nt);
      p3 = p3 && (a3 > nt);
    }
  }

  // ---- publish; both waves build final list (low half first) ---------------
#pragma unroll
  for (int k = 0; k < 10; ++k) {
    mvv[w][k][lane] = hv[k];
    mjj[w][k][lane] = hj[k];
  }
  __syncthreads();

  float fv[10];
  int fj[10];
  if (w == 0) {
    // own list IS the low half
#pragma unroll
    for (int k = 0; k < 10; ++k) { fv[k] = hv[k]; fj[k] = hj[k]; }
    // insert partner (high half) with strict >
#pragma unroll
    for (int q = 0; q < 10; ++q) {
      float v = mvv[1][q][lane];
      int jn = mjj[1][q][lane];
      if (v > fv[9]) TOP10_INSERT(fv, fj, v, jn);
    }
  } else {
    // base = partner (low half), then insert own (high half)
#pragma unroll
    for (int k = 0; k < 10; ++k) { fv[k] = mvv[0][k][lane]; fj[k] = mjj[0][k][lane]; }
#pragma unroll
    for (int q = 0; q < 10; ++q) {
      float v = hv[q];
      int jn = hj[q];
      if (v > fv[9]) TOP10_INSERT(fv, fj, v, jn);
    }
  }

  // ---- epilogue: register row compose via readlane; dense one-pass write ---
  // Both waves hold the full merged top-10 for all 64 rows (lane l = row
  // r0+l), so wave w emits rows r0+w*32 .. r0+w*32+31. For each row, the
  // owner lane's 10 (j,val) pairs become SGPRs via v_readlane (owner is
  // wave-uniform); each lane composes its 8 floats of the row (lo: global
  // idx [4*lane,4*lane+4), hi: [256+4*lane,...)) with branchless selects.
  // Pure register dataflow -> nothing to reorder; one coalesced 2KB row
  // write, each output line touched exactly once.
  float oval[10];
#pragma unroll
  for (int k = 0; k < 10; ++k) oval[k] = gateb / (1.f + __expf(-fv[k]));

  const int owner_base = w << 5;
#pragma unroll 2
  for (int r = 0; r < 32; ++r) {
    const int owner = owner_base | r;
    nf4 lo = {0.f, 0.f, 0.f, 0.f};
    nf4 hi = {0.f, 0.f, 0.f, 0.f};
#pragma unroll
    for (int k = 0; k < 10; ++k) {
      const int sj = __builtin_amdgcn_readlane(fj[k], owner);
      const float sv =
          __int_as_float(__builtin_amdgcn_readlane(__float_as_int(oval[k]), owner));
      const int half = sj >> 8;          // uniform
      const int lane_tgt = (sj >> 2) & 63;  // uniform
      const int elem = sj & 3;           // uniform
      const bool lm = (lane == lane_tgt);
      if (half == 0) {                   // uniform branch
        lo.x = (lm && elem == 0) ? sv : lo.x;
        lo.y = (lm && elem == 1) ? sv : lo.y;
        lo.z = (lm && elem == 2) ? sv : lo.z;
        lo.w = (lm && elem == 3) ? sv : lo.w;
      } else {
        hi.x = (lm && elem == 0) ? sv : hi.x;
        hi.y = (lm && elem == 1) ? sv : hi.y;
        hi.z = (lm && elem == 2) ? sv : hi.z;
        hi.w = (lm && elem == 3) ? sv : hi.w;
      }
    }
    nf4* obase = reinterpret_cast<nf4*>(out + ((size_t)(r0 + owner) << 9));
    obase[lane] = lo;          // floats [0,256): fully coalesced dwordx4
    obase[lane + 64] = hi;     // floats [256,512)
  }
}

extern "C" void kernel_launch(void* const* d_in, const int* in_sizes, int n_in,
                              void* d_out, int out_size, void* d_ws,
                              size_t ws_size, hipStream_t stream) {
  const float* ctx = (const float*)d_in[0];
  const float* emb = (const float*)d_in[1];
  const float* W1 = (const float*)d_in[2];
  const float* b1 = (const float*)d_in[3];
  const float* W2 = (const float*)d_in[4];
  const float* b2 = (const float*)d_in[5];
  const float* Wg = (const float*)d_in[6];
  const float* bg = (const float*)d_in[7];
  float* out = (float*)d_out;
  float* wws = (float*)d_ws;            // 256*32 floats: c^2
  float* gws = wws + BATCH * EMBED_DIM; // 256 floats: gate

  cdm_k1<<<BATCH, 256, 0, stream>>>(ctx, W1, b1, W2, b2, Wg, bg, wws, gws);
  cdm_k2<<<2048, 128, 0, stream>>>(emb, wws, gws, out);
}

// Round 3
// 368.471 us; speedup vs baseline: 1.1074x; 1.1074x over previous
//
#include <hip/hip_runtime.h>
#include <hip/hip_bf16.h>

// CausalDiscoveryModule: B=256, N=512, E=32, IN=512, K=10
// out[b,i,j] = gate_b * sigmoid(logit) on per-(b,i)-row top-10 of j, else 0
// logit = sum_e (c_b^2 * emb_i)[e] * emb_j[e]
//
// R8 (base = R7 compute/merge; epilogue rewritten again):
//  - R7 post-mortem: dense one-pass write worked (WRITE_SIZE=262144KB exactly,
//    FETCH ~1.3MB) but the readlane+select compose is ~120 VALU ops/row ->
//    k2 went VALU-bound (VALUBusy 62%, 17% HBM, 194us; R5 was ~155us).
//  - R8 epilogue: LDS row-compose (the cheap R6 idea) done CORRECTLY:
//    * R6 failed because nothing ordered the float* scatter vs nf4* reads;
//      hipcc's alias analysis reordered them. HW DS is in-order per wave,
//      but that's not a compiler contract.
//    * Fix: asm volatile("" ::: "memory") compiler fences between
//      scatter -> read -> rezero. Pure compile-time; DS pipe order does the
//      rest. 4 rows per phase so the 10 scatter ds_writes cover 4 owner
//      lanes in parallel (exec-masked), ~8 instr/row total vs R7's ~120.
//    * rowbuf [2][4][512]f = 16KB overlays the dead merge arrays (union);
//      one extra __syncthreads before reuse. LDS 16.4KB -> grid (8 blk/CU)
//      still the occupancy limit, not LDS.

#define NUM_VARS 512
#define EMBED_DIM 32
#define IN_DIM 512
#define BATCH 256

typedef float nf4 __attribute__((ext_vector_type(4)));
typedef float f2 __attribute__((ext_vector_type(2)));

// ---------------- K1: context MLP -> w = c^2 [256][32], gate [256] ----------
__global__ __launch_bounds__(256) void cdm_k1(
    const float* __restrict__ ctx, const float* __restrict__ W1,
    const float* __restrict__ b1, const float* __restrict__ W2,
    const float* __restrict__ b2, const float* __restrict__ Wg,
    const float* __restrict__ bg, float* __restrict__ wws,
    float* __restrict__ gws) {
  const int bb = blockIdx.x;
  const int t = threadIdx.x;
  __shared__ float xs[512];
  __shared__ float psum[32][9];   // +1 pad
  __shared__ float hs[32];
  __shared__ float cs[32];
  const float* x = ctx + (bb << 9);
  xs[t] = x[t];
  xs[t + 256] = x[t + 256];
  __syncthreads();
  {
    const int e = t >> 3, part = t & 7;
    const float* wrow = W1 + e * 512 + part * 64;
    const float* xp = xs + part * 64;
    float a = 0.f;
#pragma unroll
    for (int m = 0; m < 64; ++m) a = fmaf(wrow[m], xp[m], a);
    psum[e][part] = a;
  }
  __syncthreads();
  if (t < 32) {
    float a = 0.f;
#pragma unroll
    for (int p = 0; p < 8; ++p) a += psum[t][p];
    hs[t] = fmaxf(a + b1[t], 0.f);
  }
  __syncthreads();
  if (t < 32) {
    const float* wrow = W2 + (t << 5);
    float a = 0.f;
#pragma unroll
    for (int k = 0; k < 32; ++k) a = fmaf(wrow[k], hs[k], a);
    float c = a + b2[t];
    cs[t] = c;
    wws[(bb << 5) + t] = c * c;
  }
  __syncthreads();
  if (t == 0) {
    float a = 0.f;
#pragma unroll
    for (int k = 0; k < 32; ++k) a = fmaf(Wg[k], cs[k], a);
    float g = a + bg[0];
    gws[bb] = 1.f / (1.f + __expf(-g));
  }
}

// strict-> shift insert: equal values keep earlier-inserted (lower j) above
#define TOP10_INSERT(av, aj, v, jn)                           \
  do {                                                        \
    _Pragma("unroll") for (int k = 9; k >= 1; --k) {          \
      bool gk = (v) > av[k];                                  \
      bool gk1 = (v) > av[k - 1];                             \
      av[k] = gk ? (gk1 ? av[k - 1] : (v)) : av[k];           \
      aj[k] = gk ? (gk1 ? aj[k - 1] : (jn)) : aj[k];          \
    }                                                         \
    bool g0 = (v) > av[0];                                    \
    av[0] = g0 ? (v) : av[0];                                 \
    aj[0] = g0 ? (jn) : aj[0];                                \
  } while (0)

// ---------------- K2: 2-wave block per 64 rows; exact top-10; dense write ---
__global__ __launch_bounds__(128, 4) void cdm_k2(
    const float* __restrict__ emb, const float* __restrict__ wws,
    const float* __restrict__ gws, float* __restrict__ out) {
  const int lane = threadIdx.x & 63;
  const int w = threadIdx.x >> 6;    // half 0: j in [0,256), 1: [256,512)
  const int G = __builtin_amdgcn_readfirstlane(blockIdx.x);
  const int r0 = G << 6;             // 64 rows per block, same b
  const int b = r0 >> 9;
  const int i = (r0 + lane) & 511;
  const int jbase = __builtin_amdgcn_readfirstlane(w << 8);

  // union: merge arrays (phase 1) / row-compose buffer (phase 2)
  __shared__ __align__(16) char smem_u[16384];
  float (*mvv)[10][64] = reinterpret_cast<float(*)[10][64]>(smem_u);       // [2][10][64]
  int (*mjj)[10][64] = reinterpret_cast<int(*)[10][64]>(smem_u + 5120);    // [2][10][64]
  float* rowbuf = reinterpret_cast<float*>(smem_u);                        // [2][4][512]

  // sv2[q] = (c^2)[b] * emb[i] as float2 pairs (per-lane)
  f2 sv2[16];
  {
    const f2* wb = reinterpret_cast<const f2*>(wws + (b << 5));
    const f2* ei = reinterpret_cast<const f2*>(emb + (i << 5));
#pragma unroll
    for (int q = 0; q < 16; ++q) sv2[q] = wb[q] * ei[q];
  }
  const float gateb = gws[b];

  float hv[10];
  int hj[10];
#pragma unroll
  for (int k = 0; k < 10; ++k) { hv[k] = -1e30f; hj[k] = 0; }

  const f2* eb = reinterpret_cast<const f2*>(emb);
  for (int t = 0; t < 64; ++t) {
    const int j0 = jbase + (t << 2);
    const f2* e0 = eb + ((j0 + 0) << 4);
    const f2* e1 = eb + ((j0 + 1) << 4);
    const f2* e2 = eb + ((j0 + 2) << 4);
    const f2* e3 = eb + ((j0 + 3) << 4);
    f2 c0 = {0.f, 0.f}, c1 = {0.f, 0.f}, c2 = {0.f, 0.f}, c3 = {0.f, 0.f};
#pragma unroll
    for (int q = 0; q < 16; ++q) {
      c0 += sv2[q] * e0[q];   // v_pk_fma_f32
      c1 += sv2[q] * e1[q];
      c2 += sv2[q] * e2[q];
      c3 += sv2[q] * e3[q];
    }
    float a0 = c0.x + c0.y, a1 = c1.x + c1.y;
    float a2 = c2.x + c2.y, a3 = c3.x + c3.y;

    const float thr = hv[9];
    int p0 = a0 > thr, p1 = a1 > thr, p2 = a2 > thr, p3 = a3 > thr;
    while (__any(p0 | p1 | p2 | p3)) {
      if (p0 | p1 | p2 | p3) {
        float v;
        int jn;
        if (p0) { v = a0; jn = j0; p0 = 0; }
        else if (p1) { v = a1; jn = j0 + 1; p1 = 0; }
        else if (p2) { v = a2; jn = j0 + 2; p2 = 0; }
        else { v = a3; jn = j0 + 3; p3 = 0; }
        TOP10_INSERT(hv, hj, v, jn);
      }
      const float nt = hv[9];
      p0 = p0 && (a0 > nt);
      p1 = p1 && (a1 > nt);
      p2 = p2 && (a2 > nt);
      p3 = p3 && (a3 > nt);
    }
  }

  // ---- publish; both waves build final list (low half first) ---------------
#pragma unroll
  for (int k = 0; k < 10; ++k) {
    mvv[w][k][lane] = hv[k];
    mjj[w][k][lane] = hj[k];
  }
  __syncthreads();

  float fv[10];
  int fj[10];
  if (w == 0) {
    // own list IS the low half
#pragma unroll
    for (int k = 0; k < 10; ++k) { fv[k] = hv[k]; fj[k] = hj[k]; }
    // insert partner (high half) with strict >
#pragma unroll
    for (int q = 0; q < 10; ++q) {
      float v = mvv[1][q][lane];
      int jn = mjj[1][q][lane];
      if (v > fv[9]) TOP10_INSERT(fv, fj, v, jn);
    }
  } else {
    // base = partner (low half), then insert own (high half)
#pragma unroll
    for (int k = 0; k < 10; ++k) { fv[k] = mvv[0][k][lane]; fj[k] = mjj[0][k][lane]; }
#pragma unroll
    for (int q = 0; q < 10; ++q) {
      float v = hv[q];
      int jn = hj[q];
      if (v > fv[9]) TOP10_INSERT(fv, fj, v, jn);
    }
  }

  // ---- epilogue: batched LDS row compose; dense one-pass coalesced write ---
  // Lane l of wave w holds the merged top-10 of row r0+l. Wave w emits rows
  // r0+w*32 .. r0+w*32+31 in 8 phases of 4 rows:
  //   scatter(4 owner lanes x 10 ds_write) | fence | 8x ds_read_b128 +
  //   8x global_store_dwordx4 | fence | rezero(10 ds_write) | fence
  // Fences are compile-time only (asm "" memory clobber): they stop hipcc's
  // alias analysis from reordering float*-scatter vs nf4*-read (the R6 bug);
  // the HW DS pipe is in-order within a wave, which provides data visibility.
  float oval[10];
#pragma unroll
  for (int k = 0; k < 10; ++k) oval[k] = gateb / (1.f + __expf(-fv[k]));

  __syncthreads();   // merge-array reads (both waves) done before overlay reuse

  float* rbw = rowbuf + (w << 11);          // wave-private [4][512]
  nf4* rbw4 = reinterpret_cast<nf4*>(rbw);  // 512 nf4
  {
    const nf4 z4 = {0.f, 0.f, 0.f, 0.f};
#pragma unroll
    for (int q = 0; q < 8; ++q) rbw4[(q << 6) + lane] = z4;
  }
  asm volatile("" ::: "memory");

  for (int p = 0; p < 8; ++p) {
    const int rbase = (w << 5) | (p << 2);  // block-relative first row of phase
    const bool own = (lane >= rbase) && (lane < rbase + 4);
    const int slot = lane & 3;              // rbase % 4 == 0
    if (own) {
      float* dst = rbw + (slot << 9);
#pragma unroll
      for (int k = 0; k < 10; ++k) dst[fj[k]] = oval[k];
    }
    asm volatile("" ::: "memory");   // scatter before reads
#pragma unroll
    for (int s = 0; s < 4; ++s) {
      nf4 lo = rbw4[(s << 7) + lane];        // bytes [0,1024) of row s
      nf4 hi = rbw4[(s << 7) + 64 + lane];   // bytes [1024,2048)
      nf4* ob = reinterpret_cast<nf4*>(out + ((size_t)(r0 + rbase + s) << 9));
      ob[lane] = lo;                         // fully coalesced dwordx4
      ob[lane + 64] = hi;
    }
    asm volatile("" ::: "memory");   // reads before rezero
    if (own) {
      float* dst = rbw + (slot << 9);
#pragma unroll
      for (int k = 0; k < 10; ++k) dst[fj[k]] = 0.f;
    }
    asm volatile("" ::: "memory");   // rezero before next phase's scatter
  }
}

extern "C" void kernel_launch(void* const* d_in, const int* in_sizes, int n_in,
                              void* d_out, int out_size, void* d_ws,
                              size_t ws_size, hipStream_t stream) {
  const float* ctx = (const float*)d_in[0];
  const float* emb = (const float*)d_in[1];
  const float* W1 = (const float*)d_in[2];
  const float* b1 = (const float*)d_in[3];
  const float* W2 = (const float*)d_in[4];
  const float* b2 = (const float*)d_in[5];
  const float* Wg = (const float*)d_in[6];
  const float* bg = (const float*)d_in[7];
  float* out = (float*)d_out;
  float* wws = (float*)d_ws;            // 256*32 floats: c^2
  float* gws = wws + BATCH * EMBED_DIM; // 256 floats: gate

  cdm_k1<<<BATCH, 256, 0, stream>>>(ctx, W1, b1, W2, b2, Wg, bg, wws, gws);
  cdm_k2<<<2048, 128, 0, stream>>>(emb, wws, gws, out);
}